// Round 1
// baseline (854.502 us; speedup 1.0000x reference)
//
#include <hip/hip_runtime.h>

#define NTOK 8192
#define DDIM 1024
#define HDIM 2048
#define NEXP 8

typedef __attribute__((ext_vector_type(8))) short short8;
typedef __attribute__((ext_vector_type(4))) float f32x4;

static __device__ __forceinline__ unsigned short f2bf(float f){
  unsigned u = __builtin_bit_cast(unsigned, f);
  u += 0x7fffu + ((u >> 16) & 1u);
  return (unsigned short)(u >> 16);
}
static __device__ __forceinline__ float bf2f(unsigned short s){
  unsigned u = ((unsigned)s) << 16;
  return __builtin_bit_cast(float, u);
}

// ---------------- transpose + f32->bf16 convert: src [R][C] f32 -> dst [C][R] bf16, per expert (z)
__global__ __launch_bounds__(256) void transpose_cvt_kernel(const float* __restrict__ src,
    unsigned short* __restrict__ dst, int R, int C){
  int e = blockIdx.z;
  src += (size_t)e * R * C;
  dst += (size_t)e * R * C;
  __shared__ float tile[32][33];
  int c0 = blockIdx.x * 32, r0 = blockIdx.y * 32;
  int t = threadIdx.x;
  {
    int lr = t >> 3, lc = (t & 7) * 4;
    float4 v = *(const float4*)&src[(size_t)(r0 + lr) * C + c0 + lc];
    tile[lr][lc + 0] = v.x; tile[lr][lc + 1] = v.y;
    tile[lr][lc + 2] = v.z; tile[lr][lc + 3] = v.w;
  }
  __syncthreads();
  {
    int lc = t >> 3, lr = (t & 7) * 4;
    ushort4 o;
    o.x = f2bf(tile[lr + 0][lc]);
    o.y = f2bf(tile[lr + 1][lc]);
    o.z = f2bf(tile[lr + 2][lc]);
    o.w = f2bf(tile[lr + 3][lc]);
    *(ushort4*)&dst[(size_t)(c0 + lc) * R + r0 + lr] = o;
  }
}

// ---------------- gating: one wave per token
__global__ __launch_bounds__(256) void gate_kernel(const float* __restrict__ x,
    const float* __restrict__ Wg, const float* __restrict__ bg,
    int* __restrict__ cnt, int* __restrict__ toklist, float* __restrict__ wlist){
  int lane = threadIdx.x & 63;
  int n = blockIdx.x * 4 + (threadIdx.x >> 6);
  float acc[8] = {0,0,0,0,0,0,0,0};
  for(int d = lane; d < DDIM; d += 64){
    float xv = x[(size_t)n * DDIM + d];
    const float4* wg = (const float4*)&Wg[d * NEXP];
    float4 a = wg[0], b = wg[1];
    acc[0] += xv * a.x; acc[1] += xv * a.y; acc[2] += xv * a.z; acc[3] += xv * a.w;
    acc[4] += xv * b.x; acc[5] += xv * b.y; acc[6] += xv * b.z; acc[7] += xv * b.w;
  }
  #pragma unroll
  for(int e = 0; e < 8; e++){
    #pragma unroll
    for(int o = 32; o; o >>= 1) acc[e] += __shfl_xor(acc[e], o);
  }
  float l[8];
  #pragma unroll
  for(int e = 0; e < 8; e++) l[e] = acc[e] + bg[e];
  int i0 = 0; float l0 = l[0];
  #pragma unroll
  for(int e = 1; e < 8; e++) if(l[e] > l0){ l0 = l[e]; i0 = e; }
  int i1 = -1; float l1 = -3.4e38f;
  #pragma unroll
  for(int e = 0; e < 8; e++) if(e != i0 && l[e] > l1){ l1 = l[e]; i1 = e; }
  float w0 = 1.0f / (1.0f + expf(l1 - l0));   // = softmax over the 2 selected logits
  float w1 = 1.0f - w0;
  if(lane == 0){
    int p0 = atomicAdd(&cnt[i0], 1);
    toklist[i0 * NTOK + p0] = n; wlist[i0 * NTOK + p0] = w0;
    int p1 = atomicAdd(&cnt[i1], 1);
    toklist[i1 * NTOK + p1] = n; wlist[i1 * NTOK + p1] = w1;
  }
}

__global__ void prefix_kernel(const int* __restrict__ cnt, int* __restrict__ base){
  if(threadIdx.x == 0){
    int s = 0;
    for(int e = 0; e < NEXP; e++){ base[e] = s; s += cnt[e]; }
  }
}

// ---------------- grouped GEMM1: h_pre[slot][H] (bf16) = gather(x)[128] x W1T[e], +b1 in epilogue
__global__ __launch_bounds__(256) void gemm1_kernel(const float* __restrict__ x,
    const unsigned short* __restrict__ W1T, const float* __restrict__ b1,
    const int* __restrict__ cnt, const int* __restrict__ base,
    const int* __restrict__ toklist, unsigned short* __restrict__ hbuf){
  int e = blockIdx.z;
  int cnt_e = cnt[e];
  int row0 = blockIdx.y * 128;
  if(row0 >= cnt_e) return;
  int col0 = blockIdx.x * 128;
  __shared__ __align__(16) short A_s[128 * 72];  // pad 72: 144B stride -> ~2-way banks
  __shared__ __align__(16) short B_s[128 * 72];  // stored [col][k]
  __shared__ int tok_s[128];
  int t = threadIdx.x;
  if(t < 128){
    int r = row0 + t;
    tok_s[t] = (r < cnt_e) ? toklist[e * NTOK + r] : 0;
  }
  __syncthreads();
  int lane = t & 63, w = t >> 6, wr = w >> 1, wc = w & 1;
  int fr = lane & 15, fg = lane >> 4;
  int sr = t >> 1, sq = (t & 1) * 32;
  const unsigned short* W1e = W1T + (size_t)e * HDIM * DDIM;
  const float* xsrc_row = x + (size_t)tok_s[sr] * DDIM + sq;
  const unsigned short* bsrc_row = W1e + (size_t)(col0 + sr) * DDIM + sq;
  f32x4 acc[4][4] = {};
  for(int k0 = 0; k0 < DDIM; k0 += 64){
    #pragma unroll
    for(int i = 0; i < 4; i++){           // stage A: f32 -> bf16
      float4 a = *(const float4*)(xsrc_row + k0 + i * 8);
      float4 b = *(const float4*)(xsrc_row + k0 + i * 8 + 4);
      uint4 p;
      p.x = (unsigned)f2bf(a.x) | ((unsigned)f2bf(a.y) << 16);
      p.y = (unsigned)f2bf(a.z) | ((unsigned)f2bf(a.w) << 16);
      p.z = (unsigned)f2bf(b.x) | ((unsigned)f2bf(b.y) << 16);
      p.w = (unsigned)f2bf(b.z) | ((unsigned)f2bf(b.w) << 16);
      *(uint4*)&A_s[sr * 72 + sq + i * 8] = p;
    }
    {
      const uint4* src = (const uint4*)(bsrc_row + k0);   // stage B: bf16 copy
      #pragma unroll
      for(int i = 0; i < 4; i++){
        uint4 v = src[i];
        *(uint4*)&B_s[sr * 72 + sq + i * 8] = v;
      }
    }
    __syncthreads();
    #pragma unroll
    for(int kk = 0; kk < 64; kk += 32){
      short8 af[4], bq[4];
      #pragma unroll
      for(int m = 0; m < 4; m++) af[m] = *(const short8*)&A_s[(wr*64 + m*16 + fr)*72 + kk + fg*8];
      #pragma unroll
      for(int nn = 0; nn < 4; nn++) bq[nn] = *(const short8*)&B_s[(wc*64 + nn*16 + fr)*72 + kk + fg*8];
      #pragma unroll
      for(int m = 0; m < 4; m++)
        #pragma unroll
        for(int nn = 0; nn < 4; nn++)
          acc[m][nn] = __builtin_amdgcn_mfma_f32_16x16x32_bf16(af[m], bq[nn], acc[m][nn], 0, 0, 0);
    }
    __syncthreads();
  }
  int slot0 = base[e] + row0;
  #pragma unroll
  for(int m = 0; m < 4; m++){
    #pragma unroll
    for(int i = 0; i < 4; i++){
      int rr = wr*64 + m*16 + fg*4 + i;       // D: row=(lane>>4)*4+i, col=lane&15
      if(row0 + rr < cnt_e){
        size_t rowoff = (size_t)(slot0 + rr) * HDIM;
        #pragma unroll
        for(int nn = 0; nn < 4; nn++){
          int c = col0 + wc*64 + nn*16 + fr;
          float v = acc[m][nn][i] + b1[e * HDIM + c];
          hbuf[rowoff + c] = f2bf(v);
        }
      }
    }
  }
}

// ---------------- rowwise LayerNorm + exact GELU, in-place on hbuf
__global__ __launch_bounds__(256) void ln_gelu_kernel(unsigned short* __restrict__ hbuf,
    const float* __restrict__ ln_g, const float* __restrict__ ln_b,
    const int* __restrict__ cnt, const int* __restrict__ base){
  int e = blockIdx.y, pos = blockIdx.x;
  if(pos >= cnt[e]) return;
  size_t off = (size_t)(base[e] + pos) * HDIM;
  int t = threadIdx.x;
  uint4 pk = *(const uint4*)&hbuf[off + t * 8];
  float v[8];
  {
    unsigned uu[4] = {pk.x, pk.y, pk.z, pk.w};
    #pragma unroll
    for(int j = 0; j < 4; j++){
      v[2*j]   = bf2f((unsigned short)(uu[j] & 0xffffu));
      v[2*j+1] = bf2f((unsigned short)(uu[j] >> 16));
    }
  }
  float s = 0.f, ss = 0.f;
  #pragma unroll
  for(int j = 0; j < 8; j++){ s += v[j]; ss += v[j] * v[j]; }
  #pragma unroll
  for(int o = 32; o; o >>= 1){ s += __shfl_xor(s, o); ss += __shfl_xor(ss, o); }
  __shared__ float red[8];
  if((t & 63) == 0){ red[t >> 6] = s; red[4 + (t >> 6)] = ss; }
  __syncthreads();
  s  = red[0] + red[1] + red[2] + red[3];
  ss = red[4] + red[5] + red[6] + red[7];
  float mean = s * (1.0f / HDIM);
  float var  = ss * (1.0f / HDIM) - mean * mean;
  float rstd = rsqrtf(var + 1e-5f);
  const float* g  = ln_g + e * HDIM + t * 8;
  const float* bb = ln_b + e * HDIM + t * 8;
  unsigned ou[4];
  #pragma unroll
  for(int j = 0; j < 4; j++){
    float y0 = (v[2*j]   - mean) * rstd * g[2*j]   + bb[2*j];
    float y1 = (v[2*j+1] - mean) * rstd * g[2*j+1] + bb[2*j+1];
    y0 = 0.5f * y0 * (1.0f + erff(y0 * 0.70710678118654752f));
    y1 = 0.5f * y1 * (1.0f + erff(y1 * 0.70710678118654752f));
    ou[j] = (unsigned)f2bf(y0) | ((unsigned)f2bf(y1) << 16);
  }
  uint4 o4; o4.x = ou[0]; o4.y = ou[1]; o4.z = ou[2]; o4.w = ou[3];
  *(uint4*)&hbuf[off + t * 8] = o4;
}

// ---------------- grouped GEMM2: eo = h_act x W2T[e], +b2, weighted scatter-add into out
__global__ __launch_bounds__(256) void gemm2_kernel(const unsigned short* __restrict__ hbuf,
    const unsigned short* __restrict__ W2T, const float* __restrict__ b2,
    const int* __restrict__ cnt, const int* __restrict__ base,
    const int* __restrict__ toklist, const float* __restrict__ wlist,
    float* __restrict__ out){
  int e = blockIdx.z;
  int cnt_e = cnt[e];
  int row0 = blockIdx.y * 128;
  if(row0 >= cnt_e) return;
  int col0 = blockIdx.x * 128;
  __shared__ __align__(16) short A_s[128 * 72];
  __shared__ __align__(16) short B_s[128 * 72];
  __shared__ int tok_s[128];
  __shared__ float wt_s[128];
  int t = threadIdx.x;
  if(t < 128){
    int r = row0 + t;
    tok_s[t] = (r < cnt_e) ? toklist[e * NTOK + r] : 0;
    wt_s[t]  = (r < cnt_e) ? wlist[e * NTOK + r] : 0.f;
  }
  __syncthreads();
  int lane = t & 63, w = t >> 6, wr = w >> 1, wc = w & 1;
  int fr = lane & 15, fg = lane >> 4;
  int sr = t >> 1, sq = (t & 1) * 32;
  int ebase = base[e];
  int ar = row0 + sr; if(ar >= cnt_e) ar = cnt_e - 1;  // clamp padded rows (results discarded)
  const unsigned short* asrc_row = hbuf + (size_t)(ebase + ar) * HDIM + sq;
  const unsigned short* W2e = W2T + (size_t)e * HDIM * HDIM;
  const unsigned short* bsrc_row = W2e + (size_t)(col0 + sr) * HDIM + sq;
  f32x4 acc[4][4] = {};
  for(int k0 = 0; k0 < HDIM; k0 += 64){
    {
      const uint4* srcA = (const uint4*)(asrc_row + k0);
      const uint4* srcB = (const uint4*)(bsrc_row + k0);
      #pragma unroll
      for(int i = 0; i < 4; i++){
        uint4 va = srcA[i]; *(uint4*)&A_s[sr * 72 + sq + i * 8] = va;
        uint4 vb = srcB[i]; *(uint4*)&B_s[sr * 72 + sq + i * 8] = vb;
      }
    }
    __syncthreads();
    #pragma unroll
    for(int kk = 0; kk < 64; kk += 32){
      short8 af[4], bq[4];
      #pragma unroll
      for(int m = 0; m < 4; m++) af[m] = *(const short8*)&A_s[(wr*64 + m*16 + fr)*72 + kk + fg*8];
      #pragma unroll
      for(int nn = 0; nn < 4; nn++) bq[nn] = *(const short8*)&B_s[(wc*64 + nn*16 + fr)*72 + kk + fg*8];
      #pragma unroll
      for(int m = 0; m < 4; m++)
        #pragma unroll
        for(int nn = 0; nn < 4; nn++)
          acc[m][nn] = __builtin_amdgcn_mfma_f32_16x16x32_bf16(af[m], bq[nn], acc[m][nn], 0, 0, 0);
    }
    __syncthreads();
  }
  #pragma unroll
  for(int m = 0; m < 4; m++){
    #pragma unroll
    for(int i = 0; i < 4; i++){
      int rr = wr*64 + m*16 + fg*4 + i;
      if(row0 + rr < cnt_e){
        int tk = tok_s[rr];
        float wgt = wt_s[rr];
        size_t obase = (size_t)tk * HDIM;
        #pragma unroll
        for(int nn = 0; nn < 4; nn++){
          int c = col0 + wc*64 + nn*16 + fr;
          float v = acc[m][nn][i] + b2[e * HDIM + c];
          atomicAdd(&out[obase + c], v * wgt);
        }
      }
    }
  }
}

extern "C" void kernel_launch(void* const* d_in, const int* in_sizes, int n_in,
                              void* d_out, int out_size, void* d_ws, size_t ws_size,
                              hipStream_t stream){
  (void)in_sizes; (void)n_in; (void)out_size; (void)ws_size;
  const float* x   = (const float*)d_in[0];
  const float* W1  = (const float*)d_in[1];
  const float* b1  = (const float*)d_in[2];
  const float* lng = (const float*)d_in[3];
  const float* lnb = (const float*)d_in[4];
  const float* W2  = (const float*)d_in[5];
  const float* b2  = (const float*)d_in[6];
  const float* Wg  = (const float*)d_in[7];
  const float* bg  = (const float*)d_in[8];
  float* out = (float*)d_out;

  char* ws = (char*)d_ws;
  size_t o = 0;
  unsigned short* W1T  = (unsigned short*)(ws + o); o += (size_t)NEXP * HDIM * DDIM * 2;   // 33.5 MB
  unsigned short* W2T  = (unsigned short*)(ws + o); o += (size_t)NEXP * HDIM * HDIM * 2;   // 67 MB
  unsigned short* hbuf = (unsigned short*)(ws + o); o += (size_t)(NTOK * 2 + 128) * HDIM * 2; // 67.6 MB
  int*   cnt     = (int*)(ws + o);   o += 128;
  int*   basep   = (int*)(ws + o);   o += 128;
  int*   toklist = (int*)(ws + o);   o += (size_t)NEXP * NTOK * 4;
  float* wlist   = (float*)(ws + o); o += (size_t)NEXP * NTOK * 4;

  hipMemsetAsync(d_out, 0, (size_t)NTOK * HDIM * sizeof(float), stream);
  hipMemsetAsync(cnt, 0, 32, stream);
  transpose_cvt_kernel<<<dim3(HDIM/32, DDIM/32, NEXP), 256, 0, stream>>>(W1, W1T, DDIM, HDIM);
  transpose_cvt_kernel<<<dim3(HDIM/32, HDIM/32, NEXP), 256, 0, stream>>>(W2, W2T, HDIM, HDIM);
  gate_kernel<<<NTOK/4, 256, 0, stream>>>(x, Wg, bg, cnt, toklist, wlist);
  prefix_kernel<<<1, 64, 0, stream>>>(cnt, basep);
  gemm1_kernel<<<dim3(HDIM/128, NTOK/128, NEXP), 256, 0, stream>>>(x, W1T, b1, cnt, basep, toklist, hbuf);
  ln_gelu_kernel<<<dim3(NTOK, NEXP), 256, 0, stream>>>(hbuf, lng, lnb, cnt, basep);
  gemm2_kernel<<<dim3(HDIM/128, NTOK/128, NEXP), 256, 0, stream>>>(hbuf, W2T, b2, cnt, basep, toklist, wlist, out);
}

// Round 2
// 834.356 us; speedup vs baseline: 1.0241x; 1.0241x over previous
//
#include <hip/hip_runtime.h>

#define NTOK 8192
#define DDIM 1024
#define HDIM 2048
#define NEXP 8

typedef __attribute__((ext_vector_type(8))) short short8;
typedef __attribute__((ext_vector_type(4))) float f32x4;

static __device__ __forceinline__ unsigned short f2bf(float f){
  unsigned u = __builtin_bit_cast(unsigned, f);
  u += 0x7fffu + ((u >> 16) & 1u);
  return (unsigned short)(u >> 16);
}
static __device__ __forceinline__ float bf2f(unsigned short s){
  unsigned u = ((unsigned)s) << 16;
  return __builtin_bit_cast(float, u);
}

// async global->LDS, 16B per lane. LDS dest = wave-uniform base + lane*16.
static __device__ __forceinline__ void gload16(const void* g, void* l){
  __builtin_amdgcn_global_load_lds((const __attribute__((address_space(1))) void*)g,
                                   (__attribute__((address_space(3))) void*)l, 16, 0, 0);
}

// ---------------- x f32 -> bf16 convert
__global__ __launch_bounds__(256) void cvt_x_kernel(const float* __restrict__ x,
    unsigned short* __restrict__ xbf){
  size_t i = ((size_t)blockIdx.x * 256 + threadIdx.x) * 8;
  float4 a = *(const float4*)&x[i];
  float4 b = *(const float4*)&x[i + 4];
  uint4 p;
  p.x = (unsigned)f2bf(a.x) | ((unsigned)f2bf(a.y) << 16);
  p.y = (unsigned)f2bf(a.z) | ((unsigned)f2bf(a.w) << 16);
  p.z = (unsigned)f2bf(b.x) | ((unsigned)f2bf(b.y) << 16);
  p.w = (unsigned)f2bf(b.z) | ((unsigned)f2bf(b.w) << 16);
  *(uint4*)&xbf[i] = p;
}

// ---------------- transpose + f32->bf16: src [R][C] f32 -> dst [C][R] bf16, per expert (z)
__global__ __launch_bounds__(256) void transpose_cvt_kernel(const float* __restrict__ src,
    unsigned short* __restrict__ dst, int R, int C){
  int e = blockIdx.z;
  src += (size_t)e * R * C;
  dst += (size_t)e * R * C;
  __shared__ float tile[32][33];
  int c0 = blockIdx.x * 32, r0 = blockIdx.y * 32;
  int t = threadIdx.x;
  {
    int lr = t >> 3, lc = (t & 7) * 4;
    float4 v = *(const float4*)&src[(size_t)(r0 + lr) * C + c0 + lc];
    tile[lr][lc + 0] = v.x; tile[lr][lc + 1] = v.y;
    tile[lr][lc + 2] = v.z; tile[lr][lc + 3] = v.w;
  }
  __syncthreads();
  {
    int lc = t >> 3, lr = (t & 7) * 4;
    ushort4 o;
    o.x = f2bf(tile[lr + 0][lc]);
    o.y = f2bf(tile[lr + 1][lc]);
    o.z = f2bf(tile[lr + 2][lc]);
    o.w = f2bf(tile[lr + 3][lc]);
    *(ushort4*)&dst[(size_t)(c0 + lc) * R + r0 + lr] = o;
  }
}

// ---------------- gating: one wave per token
__global__ __launch_bounds__(256) void gate_kernel(const float* __restrict__ x,
    const float* __restrict__ Wg, const float* __restrict__ bg,
    int* __restrict__ cnt, int* __restrict__ toklist, float* __restrict__ wlist){
  int lane = threadIdx.x & 63;
  int n = blockIdx.x * 4 + (threadIdx.x >> 6);
  float acc[8] = {0,0,0,0,0,0,0,0};
  for(int d = lane; d < DDIM; d += 64){
    float xv = x[(size_t)n * DDIM + d];
    const float4* wg = (const float4*)&Wg[d * NEXP];
    float4 a = wg[0], b = wg[1];
    acc[0] += xv * a.x; acc[1] += xv * a.y; acc[2] += xv * a.z; acc[3] += xv * a.w;
    acc[4] += xv * b.x; acc[5] += xv * b.y; acc[6] += xv * b.z; acc[7] += xv * b.w;
  }
  #pragma unroll
  for(int e = 0; e < 8; e++){
    #pragma unroll
    for(int o = 32; o; o >>= 1) acc[e] += __shfl_xor(acc[e], o);
  }
  float l[8];
  #pragma unroll
  for(int e = 0; e < 8; e++) l[e] = acc[e] + bg[e];
  int i0 = 0; float l0 = l[0];
  #pragma unroll
  for(int e = 1; e < 8; e++) if(l[e] > l0){ l0 = l[e]; i0 = e; }
  int i1 = -1; float l1 = -3.4e38f;
  #pragma unroll
  for(int e = 0; e < 8; e++) if(e != i0 && l[e] > l1){ l1 = l[e]; i1 = e; }
  float w0 = 1.0f / (1.0f + expf(l1 - l0));   // = softmax over the 2 selected logits
  float w1 = 1.0f - w0;
  if(lane == 0){
    int p0 = atomicAdd(&cnt[i0], 1);
    toklist[i0 * NTOK + p0] = n; wlist[i0 * NTOK + p0] = w0;
    int p1 = atomicAdd(&cnt[i1], 1);
    toklist[i1 * NTOK + p1] = n; wlist[i1 * NTOK + p1] = w1;
  }
}

__global__ void prefix_kernel(const int* __restrict__ cnt, int* __restrict__ base){
  if(threadIdx.x == 0){
    int s = 0;
    for(int e = 0; e < NEXP; e++){ base[e] = s; s += cnt[e]; }
  }
}

// ---------------- grouped GEMM1: h_pre[slot][H] (bf16) = gather(xbf) x W1T[e]^T, +b1
// m97 structure: 128x128 tile, BK=64, global_load_lds(16B), XOR-swizzled chunks.
__global__ __launch_bounds__(256) void gemm1_kernel(const unsigned short* __restrict__ xbf,
    const unsigned short* __restrict__ W1T, const float* __restrict__ b1,
    const int* __restrict__ cnt, const int* __restrict__ base,
    const int* __restrict__ toklist, unsigned short* __restrict__ hbuf){
  int e = blockIdx.z;
  int cnt_e = cnt[e];
  int row0 = blockIdx.y * 128;
  if(row0 >= cnt_e) return;
  int col0 = blockIdx.x * 128;
  __shared__ __align__(16) unsigned short A_s[128 * 64];
  __shared__ __align__(16) unsigned short B_s[128 * 64];
  __shared__ int tok_s[128];
  int t = threadIdx.x;
  if(t < 128){
    int r = row0 + t;
    tok_s[t] = (r < cnt_e) ? toklist[e * NTOK + r] : toklist[e * NTOK + cnt_e - 1];
  }
  __syncthreads();
  int lane = t & 63, w = t >> 6, wr = w >> 1, wc = w & 1;
  int fr = lane & 15, fg = lane >> 4;
  // staging geometry: issue i stages rows [i*32, i*32+32); thread covers row t/8,
  // physical chunk t%8 (16B). Source chunk is inverse-swizzled: c ^ (row&7).
  int srow = t >> 3;
  int schunk = ((t & 7) ^ (srow & 7)) * 8;
  const unsigned short* W1e = W1T + (size_t)e * HDIM * DDIM;
  const unsigned short* aptr[4];
  const unsigned short* bptr[4];
  #pragma unroll
  for(int i = 0; i < 4; i++){
    int r = i * 32 + srow;
    aptr[i] = xbf + (size_t)tok_s[r] * DDIM + schunk;
    bptr[i] = W1e + (size_t)(col0 + r) * DDIM + schunk;
  }
  unsigned wbase = (unsigned)((t >> 6) << 10);  // wave-uniform LDS byte base
  f32x4 acc[4][4] = {};
  for(int k0 = 0; k0 < DDIM; k0 += 64){
    #pragma unroll
    for(int i = 0; i < 4; i++){
      gload16(aptr[i] + k0, (char*)A_s + i * 4096 + wbase);
      gload16(bptr[i] + k0, (char*)B_s + i * 4096 + wbase);
    }
    __syncthreads();   // vmcnt(0) drain + barrier
    #pragma unroll
    for(int kk = 0; kk < 64; kk += 32){
      int q = kk >> 3;
      int chunk = (((q + fg) ^ (fr & 7)) << 3);  // swizzled read chunk (elements)
      short8 af[4], bq[4];
      #pragma unroll
      for(int m = 0; m < 4; m++)  af[m] = *(const short8*)&A_s[(wr*64 + m*16 + fr)*64 + chunk];
      #pragma unroll
      for(int nn = 0; nn < 4; nn++) bq[nn] = *(const short8*)&B_s[(wc*64 + nn*16 + fr)*64 + chunk];
      #pragma unroll
      for(int m = 0; m < 4; m++)
        #pragma unroll
        for(int nn = 0; nn < 4; nn++)
          acc[m][nn] = __builtin_amdgcn_mfma_f32_16x16x32_bf16(af[m], bq[nn], acc[m][nn], 0, 0, 0);
    }
    __syncthreads();
  }
  int slot0 = base[e] + row0;
  #pragma unroll
  for(int m = 0; m < 4; m++){
    #pragma unroll
    for(int i = 0; i < 4; i++){
      int rr = wr*64 + m*16 + fg*4 + i;      // D: row=(lane>>4)*4+i, col=lane&15
      if(row0 + rr < cnt_e){
        size_t rowoff = (size_t)(slot0 + rr) * HDIM;
        #pragma unroll
        for(int nn = 0; nn < 4; nn++){
          int c = col0 + wc*64 + nn*16 + fr;
          float v = acc[m][nn][i] + b1[e * HDIM + c];
          hbuf[rowoff + c] = f2bf(v);
        }
      }
    }
  }
}

// ---------------- rowwise LayerNorm + exact GELU, flattened over compact slots
__global__ __launch_bounds__(256) void ln_gelu_kernel(unsigned short* __restrict__ hbuf,
    const float* __restrict__ ln_g, const float* __restrict__ ln_b,
    const int* __restrict__ base){
  int s = blockIdx.x;              // slot 0..2*NTOK-1, always valid (sum cnt == 2*NTOK)
  int e = 0;
  #pragma unroll
  for(int i = 1; i < NEXP; i++) if(s >= base[i]) e = i;
  size_t off = (size_t)s * HDIM;
  int t = threadIdx.x;
  uint4 pk = *(const uint4*)&hbuf[off + t * 8];
  float v[8];
  {
    unsigned uu[4] = {pk.x, pk.y, pk.z, pk.w};
    #pragma unroll
    for(int j = 0; j < 4; j++){
      v[2*j]   = bf2f((unsigned short)(uu[j] & 0xffffu));
      v[2*j+1] = bf2f((unsigned short)(uu[j] >> 16));
    }
  }
  float sm = 0.f, ss = 0.f;
  #pragma unroll
  for(int j = 0; j < 8; j++){ sm += v[j]; ss += v[j] * v[j]; }
  #pragma unroll
  for(int o = 32; o; o >>= 1){ sm += __shfl_xor(sm, o); ss += __shfl_xor(ss, o); }
  __shared__ float red[8];
  if((t & 63) == 0){ red[t >> 6] = sm; red[4 + (t >> 6)] = ss; }
  __syncthreads();
  sm = red[0] + red[1] + red[2] + red[3];
  ss = red[4] + red[5] + red[6] + red[7];
  float mean = sm * (1.0f / HDIM);
  float var  = ss * (1.0f / HDIM) - mean * mean;
  float rstd = rsqrtf(var + 1e-5f);
  const float* g  = ln_g + e * HDIM + t * 8;
  const float* bb = ln_b + e * HDIM + t * 8;
  unsigned ou[4];
  #pragma unroll
  for(int j = 0; j < 4; j++){
    float y0 = (v[2*j]   - mean) * rstd * g[2*j]   + bb[2*j];
    float y1 = (v[2*j+1] - mean) * rstd * g[2*j+1] + bb[2*j+1];
    y0 = 0.5f * y0 * (1.0f + erff(y0 * 0.70710678118654752f));
    y1 = 0.5f * y1 * (1.0f + erff(y1 * 0.70710678118654752f));
    ou[j] = (unsigned)f2bf(y0) | ((unsigned)f2bf(y1) << 16);
  }
  uint4 o4; o4.x = ou[0]; o4.y = ou[1]; o4.z = ou[2]; o4.w = ou[3];
  *(uint4*)&hbuf[off + t * 8] = o4;
}

// ---------------- grouped GEMM2: eo = h_act x W2T[e]^T, +b2, weighted scatter-add
__global__ __launch_bounds__(256) void gemm2_kernel(const unsigned short* __restrict__ hbuf,
    const unsigned short* __restrict__ W2T, const float* __restrict__ b2,
    const int* __restrict__ cnt, const int* __restrict__ base,
    const int* __restrict__ toklist, const float* __restrict__ wlist,
    float* __restrict__ out){
  int e = blockIdx.z;
  int cnt_e = cnt[e];
  int row0 = blockIdx.y * 128;
  if(row0 >= cnt_e) return;
  int col0 = blockIdx.x * 128;
  __shared__ __align__(16) unsigned short A_s[128 * 64];
  __shared__ __align__(16) unsigned short B_s[128 * 64];
  __shared__ int tok_s[128];
  __shared__ float wt_s[128];
  int t = threadIdx.x;
  if(t < 128){
    int r = row0 + t;
    tok_s[t] = (r < cnt_e) ? toklist[e * NTOK + r] : 0;
    wt_s[t]  = (r < cnt_e) ? wlist[e * NTOK + r] : 0.f;
  }
  __syncthreads();
  int lane = t & 63, w = t >> 6, wr = w >> 1, wc = w & 1;
  int fr = lane & 15, fg = lane >> 4;
  int srow = t >> 3;
  int schunk = ((t & 7) ^ (srow & 7)) * 8;
  int ebase = base[e];
  const unsigned short* W2e = W2T + (size_t)e * HDIM * HDIM;
  const unsigned short* aptr[4];
  const unsigned short* bptr[4];
  #pragma unroll
  for(int i = 0; i < 4; i++){
    int r = row0 + i * 32 + srow;
    if(r >= cnt_e) r = cnt_e - 1;     // clamp padded rows (results discarded)
    aptr[i] = hbuf + (size_t)(ebase + r) * HDIM + schunk;
    bptr[i] = W2e + (size_t)(col0 + i * 32 + srow) * HDIM + schunk;
  }
  unsigned wbase = (unsigned)((t >> 6) << 10);
  f32x4 acc[4][4] = {};
  for(int k0 = 0; k0 < HDIM; k0 += 64){
    #pragma unroll
    for(int i = 0; i < 4; i++){
      gload16(aptr[i] + k0, (char*)A_s + i * 4096 + wbase);
      gload16(bptr[i] + k0, (char*)B_s + i * 4096 + wbase);
    }
    __syncthreads();
    #pragma unroll
    for(int kk = 0; kk < 64; kk += 32){
      int q = kk >> 3;
      int chunk = (((q + fg) ^ (fr & 7)) << 3);
      short8 af[4], bq[4];
      #pragma unroll
      for(int m = 0; m < 4; m++)  af[m] = *(const short8*)&A_s[(wr*64 + m*16 + fr)*64 + chunk];
      #pragma unroll
      for(int nn = 0; nn < 4; nn++) bq[nn] = *(const short8*)&B_s[(wc*64 + nn*16 + fr)*64 + chunk];
      #pragma unroll
      for(int m = 0; m < 4; m++)
        #pragma unroll
        for(int nn = 0; nn < 4; nn++)
          acc[m][nn] = __builtin_amdgcn_mfma_f32_16x16x32_bf16(af[m], bq[nn], acc[m][nn], 0, 0, 0);
    }
    __syncthreads();
  }
  #pragma unroll
  for(int m = 0; m < 4; m++){
    #pragma unroll
    for(int i = 0; i < 4; i++){
      int rr = wr*64 + m*16 + fg*4 + i;
      if(row0 + rr < cnt_e){
        int tk = tok_s[rr];
        float wgt = wt_s[rr];
        size_t obase = (size_t)tk * HDIM;
        #pragma unroll
        for(int nn = 0; nn < 4; nn++){
          int c = col0 + wc*64 + nn*16 + fr;
          float v = acc[m][nn][i] + b2[e * HDIM + c];
          atomicAdd(&out[obase + c], v * wgt);
        }
      }
    }
  }
}

extern "C" void kernel_launch(void* const* d_in, const int* in_sizes, int n_in,
                              void* d_out, int out_size, void* d_ws, size_t ws_size,
                              hipStream_t stream){
  (void)in_sizes; (void)n_in; (void)out_size; (void)ws_size;
  const float* x   = (const float*)d_in[0];
  const float* W1  = (const float*)d_in[1];
  const float* b1  = (const float*)d_in[2];
  const float* lng = (const float*)d_in[3];
  const float* lnb = (const float*)d_in[4];
  const float* W2  = (const float*)d_in[5];
  const float* b2  = (const float*)d_in[6];
  const float* Wg  = (const float*)d_in[7];
  const float* bg  = (const float*)d_in[8];
  float* out = (float*)d_out;

  char* ws = (char*)d_ws;
  size_t o = 0;
  unsigned short* W1T  = (unsigned short*)(ws + o); o += (size_t)NEXP * HDIM * DDIM * 2;      // 33.5 MB
  unsigned short* W2T  = (unsigned short*)(ws + o); o += (size_t)NEXP * HDIM * HDIM * 2;      // 67 MB
  unsigned short* hbuf = (unsigned short*)(ws + o); o += (size_t)(NTOK * 2 + 128) * HDIM * 2; // 67.6 MB
  unsigned short* xbf  = (unsigned short*)(ws + o); o += (size_t)NTOK * DDIM * 2;             // 16.8 MB
  int*   cnt     = (int*)(ws + o);   o += 128;
  int*   basep   = (int*)(ws + o);   o += 128;
  int*   toklist = (int*)(ws + o);   o += (size_t)NEXP * NTOK * 4;
  float* wlist   = (float*)(ws + o); o += (size_t)NEXP * NTOK * 4;

  hipMemsetAsync(d_out, 0, (size_t)NTOK * HDIM * sizeof(float), stream);
  hipMemsetAsync(cnt, 0, 32, stream);
  cvt_x_kernel<<<NTOK * DDIM / 2048, 256, 0, stream>>>(x, xbf);
  transpose_cvt_kernel<<<dim3(HDIM/32, DDIM/32, NEXP), 256, 0, stream>>>(W1, W1T, DDIM, HDIM);
  transpose_cvt_kernel<<<dim3(HDIM/32, HDIM/32, NEXP), 256, 0, stream>>>(W2, W2T, HDIM, HDIM);
  gate_kernel<<<NTOK/4, 256, 0, stream>>>(x, Wg, bg, cnt, toklist, wlist);
  prefix_kernel<<<1, 64, 0, stream>>>(cnt, basep);
  gemm1_kernel<<<dim3(HDIM/128, NTOK/128, NEXP), 256, 0, stream>>>(xbf, W1T, b1, cnt, basep, toklist, hbuf);
  ln_gelu_kernel<<<NTOK * 2, 256, 0, stream>>>(hbuf, lng, lnb, basep);
  gemm2_kernel<<<dim3(HDIM/128, NTOK/128, NEXP), 256, 0, stream>>>(hbuf, W2T, b2, cnt, basep, toklist, wlist, out);
}